// Round 7
// baseline (627.721 us; speedup 1.0000x reference)
//
#include <hip/hip_runtime.h>
#include <hip/hip_bf16.h>
#include <stdint.h>
#include <stddef.h>

typedef __bf16 bf16_t;
typedef __bf16 bf16x8 __attribute__((ext_vector_type(8)));
typedef float f32x4 __attribute__((ext_vector_type(4)));

#define B_DIM 8192
#define K_DIM 4096
#define N_DIM 4096

typedef __attribute__((address_space(1))) const void gvoid_t;
typedef __attribute__((address_space(3))) void lvoid_t;

__device__ __forceinline__ void gload_lds16(const void* g, void* l) {
  // width-16 global->LDS DMA; LDS dest is wave-uniform base + lane*16
  __builtin_amdgcn_global_load_lds((gvoid_t*)g, (lvoid_t*)l, 16, 0, 0);
}

#define FENCE() asm volatile("" ::: "memory")
#define BARRIER() do { FENCE(); __builtin_amdgcn_s_barrier(); FENCE(); } while (0)

// ------- kernel 1 (merged prep): row L2-norm+cvt for x, cvt for W -------
__global__ __launch_bounds__(256) void prep_kernel(
    const float* __restrict__ x, const float* __restrict__ W,
    bf16_t* __restrict__ xb, bf16_t* __restrict__ Wb) {
  const int t = threadIdx.x;
  if (blockIdx.x < B_DIM) {
    const int row = blockIdx.x;
    const float4* xr = (const float4*)(x + (size_t)row * K_DIM);
    float4 v[4];
    float ss = 0.f;
#pragma unroll
    for (int i = 0; i < 4; ++i) {
      v[i] = xr[i * 256 + t];
      ss += v[i].x * v[i].x + v[i].y * v[i].y + v[i].z * v[i].z + v[i].w * v[i].w;
    }
#pragma unroll
    for (int o = 32; o > 0; o >>= 1) ss += __shfl_down(ss, o, 64);
    __shared__ float wsum[4];
    __shared__ float s_scale;
    const int lane = t & 63, wv = t >> 6;
    if (lane == 0) wsum[wv] = ss;
    __syncthreads();
    if (t == 0) {
      float s = wsum[0] + wsum[1] + wsum[2] + wsum[3];
      s_scale = 1.0f / (sqrtf(s) + 1e-4f);
    }
    __syncthreads();
    const float sc = s_scale;
    bf16_t* orow = xb + (size_t)row * K_DIM;
#pragma unroll
    for (int i = 0; i < 4; ++i) {
      union { bf16_t h[4]; uint2 u; } p;
      p.h[0] = (bf16_t)(v[i].x * sc);
      p.h[1] = (bf16_t)(v[i].y * sc);
      p.h[2] = (bf16_t)(v[i].z * sc);
      p.h[3] = (bf16_t)(v[i].w * sc);
      ((uint2*)orow)[i * 256 + t] = p.u;
    }
  } else {
    const size_t idx = (size_t)(blockIdx.x - B_DIM) * 256 + t;  // one float4 each
    float4 a = ((const float4*)W)[idx];
    union { bf16_t h[4]; uint2 u; } p;
    p.h[0] = (bf16_t)a.x;
    p.h[1] = (bf16_t)a.y;
    p.h[2] = (bf16_t)a.z;
    p.h[3] = (bf16_t)a.w;
    ((uint2*)Wb)[idx] = p.u;
  }
}

// ---------------- kernel 2: 256x256 GEMM, A direct-to-reg, B in LDS --------
// A: 8192x4096 bf16 rm; Bm: 4096x4096 bf16 rm (K-major). BK=64.
// 8 waves (2M x 4N), per-wave 128x64 out = 8x4 frags of 16x16 (mfma 16x16x32).
// R7: A-fragments are wave-private -> load global->VGPR directly (kills the
// 4x-redundant A ds_reads = 1536cy/iter of the shared LDS pipe + A DMA writes).
// B stays LDS-staged: [buf(2)][256 rows][64 cols] bf16 = 64 KiB, XOR-swizzled
// byte ^= (row&7)<<4 (linear DMA dest + pre-swizzled gsrc).
// 2 phases/iter, 3 barriers. Gate vmcnt(12) at P2: 12 newest = B(u+2) DMA (4)
// + af03(u+1) (8) -> B(u+1) landed before u+1-P1 ds_reads; af47(u) drained.
__global__ __launch_bounds__(512, 1) void gemm_kernel(
    const bf16_t* __restrict__ A, const bf16_t* __restrict__ Bm,
    const float* __restrict__ bias, float* __restrict__ C) {
  __shared__ __align__(16) char lds[65536];
  const int tid = threadIdx.x;
  const int lane = tid & 63, w = tid >> 6;
  const int wm = w >> 2, wn = w & 3;
  const int hi16 = lane >> 4;   // 0..3 (k-chunk)
  const int r16 = lane & 15;

  // XCD-contiguous swizzle (512 blocks, 512 % 8 == 0 -> bijective)
  const int bid = blockIdx.x;
  const int sid = (bid & 7) * 64 + (bid >> 3);
  const int mb = sid & 31;      // 32 M-tiles
  const int nb = sid >> 5;      // 16 N-tiles

  const char* Bg = (const char*)(Bm + (size_t)nb * 256 * K_DIM);
  // per-lane A base: row = mb*256 + wm*128 + r16, k-chunk = hi16*8 elems
  const char* Aln = (const char*)A +
      (((size_t)(mb * 256 + wm * 128 + r16)) * K_DIM + hi16 * 8) * 2;

  // stage full 256x64 B tile of K-tile kt: 4 x gload_lds16/thread
  auto STAGEB = [&](int kt) {
    const int rbase = (kt & 1) * 32768;
    const char* gb = Bg + kt * 128;
#pragma unroll
    for (int i = 0; i < 4; ++i) {
      const int qb = i * 8192 + w * 1024;          // wave-uniform LDS offset
      const int q = qb + lane * 16;                // lane's linear slot
      const int r = q >> 7;                        // logical row 0..255
      const int cb = (q & 127) ^ ((r & 7) << 4);   // inverse-swizzled col byte
      gload_lds16(gb + (size_t)r * (K_DIM * 2) + cb, lds + rbase + qb);
    }
  };
  auto LDB = [&](int n, int kq, int buf) -> bf16x8 {
    const int r = wn * 64 + n * 16 + r16;          // 0..255
    const int q = (r << 7) + (kq << 6) + hi16 * 16;
    return *(const bf16x8*)(lds + buf * 32768 + (q ^ ((r & 7) << 4)));
  };
  // A frag (m-row-block, k-byte kb, kq): 16B per lane, 16 rows x 64B pattern
  auto LDAG = [&](int m, int kb, int kq) -> bf16x8 {
    return *(const bf16x8*)(Aln + (size_t)m * 16 * (K_DIM * 2) + kb + kq * 64);
  };

  f32x4 acc[8][4] = {};
  bf16x8 af03[4][2], af47[4][2], bfr[4][2];

  // prologue: B(T0), B(T1) DMA; af03(T0) loads; wait B(T0) (12 newer in flight)
  STAGEB(0); STAGEB(1);
#pragma unroll
  for (int m = 0; m < 4; ++m)
#pragma unroll
    for (int kq = 0; kq < 2; ++kq) af03[m][kq] = LDAG(m, 0, kq);
  asm volatile("s_waitcnt vmcnt(12)" ::: "memory");
  BARRIER();

  for (int u = 0; u < 64; ++u) {
    const int cur = u & 1;
    const int un2 = (u + 2) & 63;        // wrap -> dead data, same parity
    const int kb = u * 128;              // byte k-offset of this K-tile
    const int kbn = ((u + 1) & 63) * 128;
    // ---- P1: issue af47(u); ds_read all bfr; BAR; MFMA m0-3 x n0-3
#pragma unroll
    for (int m = 0; m < 4; ++m)
#pragma unroll
      for (int kq = 0; kq < 2; ++kq) af47[m][kq] = LDAG(m + 4, kb, kq);
#pragma unroll
    for (int n = 0; n < 4; ++n)
#pragma unroll
      for (int kq = 0; kq < 2; ++kq) bfr[n][kq] = LDB(n, kq, cur);
    BARRIER();
    __builtin_amdgcn_s_setprio(1);
#pragma unroll
    for (int m = 0; m < 4; ++m)
#pragma unroll
      for (int n = 0; n < 4; ++n)
#pragma unroll
        for (int kq = 0; kq < 2; ++kq)
          acc[m][n] = __builtin_amdgcn_mfma_f32_16x16x32_bf16(af03[m][kq], bfr[n][kq], acc[m][n], 0, 0, 0);
    __builtin_amdgcn_s_setprio(0);
    BARRIER();   // all waves' bfr reads done -> staging into cur-B safe
    // ---- P2: stage B(u+2); issue af03(u+1); gate vmcnt(12); MFMA m4-7
    STAGEB(un2);
#pragma unroll
    for (int m = 0; m < 4; ++m)
#pragma unroll
      for (int kq = 0; kq < 2; ++kq) af03[m][kq] = LDAG(m, kbn, kq);
    asm volatile("s_waitcnt vmcnt(12)" ::: "memory");  // B(u+1) + af47(u) landed
    BARRIER();
    __builtin_amdgcn_s_setprio(1);
#pragma unroll
    for (int m = 0; m < 4; ++m)
#pragma unroll
      for (int n = 0; n < 4; ++n)
#pragma unroll
        for (int kq = 0; kq < 2; ++kq)
          acc[m + 4][n] = __builtin_amdgcn_mfma_f32_16x16x32_bf16(af47[m][kq], bfr[n][kq], acc[m + 4][n], 0, 0, 0);
    __builtin_amdgcn_s_setprio(0);
    // no end barrier: next P1 reads buf[nxt] (untouched this iter); next
    // cur-B write (u+1-P2) is fenced by u+1's P1-end barrier.
  }

  // epilogue: bias + ReLU, fp32 store. C/D map: col=lane&15, row=(lane>>4)*4+j
  float bv[4];
#pragma unroll
  for (int n = 0; n < 4; ++n) bv[n] = bias[nb * 256 + wn * 64 + n * 16 + r16];
#pragma unroll
  for (int m = 0; m < 8; ++m) {
    const int row0 = mb * 256 + wm * 128 + m * 16 + hi16 * 4;
#pragma unroll
    for (int j = 0; j < 4; ++j) {
      float* crow = C + (size_t)(row0 + j) * N_DIM + nb * 256 + wn * 64 + r16;
#pragma unroll
      for (int n = 0; n < 4; ++n)
        crow[n * 16] = fmaxf(acc[m][n][j] + bv[n], 0.f);
    }
  }
}

extern "C" void kernel_launch(void* const* d_in, const int* in_sizes, int n_in,
                              void* d_out, int out_size, void* d_ws, size_t ws_size,
                              hipStream_t stream) {
  const float* x = (const float*)d_in[0];
  const float* W = (const float*)d_in[1];
  const float* b = (const float*)d_in[2];
  float* out = (float*)d_out;

  bf16_t* xb = (bf16_t*)d_ws;                       // 8192*4096*2 = 64 MB
  bf16_t* Wb = xb + (size_t)B_DIM * K_DIM;          // 4096*4096*2 = 32 MB

  // 8192 norm blocks + 16384 W-convert blocks in one dispatch
  prep_kernel<<<B_DIM + (N_DIM * (size_t)K_DIM) / 4 / 256, 256, 0, stream>>>(x, W, xb, Wb);
  gemm_kernel<<<32 * 16, 512, 0, stream>>>(xb, Wb, b, out);
}

// Round 8
// 314.639 us; speedup vs baseline: 1.9951x; 1.9951x over previous
//
#include <hip/hip_runtime.h>
#include <hip/hip_bf16.h>
#include <stdint.h>
#include <stddef.h>

typedef __bf16 bf16_t;
typedef __bf16 bf16x8 __attribute__((ext_vector_type(8)));
typedef float f32x4 __attribute__((ext_vector_type(4)));

#define B_DIM 8192
#define K_DIM 4096
#define N_DIM 4096

typedef __attribute__((address_space(1))) const void gvoid_t;
typedef __attribute__((address_space(3))) void lvoid_t;

__device__ __forceinline__ void gload_lds16(const void* g, void* l) {
  // width-16 global->LDS DMA; LDS dest is wave-uniform base + lane*16
  __builtin_amdgcn_global_load_lds((gvoid_t*)g, (lvoid_t*)l, 16, 0, 0);
}

#define FENCE() asm volatile("" ::: "memory")
#define BARRIER() do { FENCE(); __builtin_amdgcn_s_barrier(); FENCE(); } while (0)

// ------- kernel 1 (merged prep): row L2-norm+cvt for x, cvt for W -------
__global__ __launch_bounds__(256) void prep_kernel(
    const float* __restrict__ x, const float* __restrict__ W,
    bf16_t* __restrict__ xb, bf16_t* __restrict__ Wb) {
  const int t = threadIdx.x;
  if (blockIdx.x < B_DIM) {
    const int row = blockIdx.x;
    const float4* xr = (const float4*)(x + (size_t)row * K_DIM);
    float4 v[4];
    float ss = 0.f;
#pragma unroll
    for (int i = 0; i < 4; ++i) {
      v[i] = xr[i * 256 + t];
      ss += v[i].x * v[i].x + v[i].y * v[i].y + v[i].z * v[i].z + v[i].w * v[i].w;
    }
#pragma unroll
    for (int o = 32; o > 0; o >>= 1) ss += __shfl_down(ss, o, 64);
    __shared__ float wsum[4];
    __shared__ float s_scale;
    const int lane = t & 63, wv = t >> 6;
    if (lane == 0) wsum[wv] = ss;
    __syncthreads();
    if (t == 0) {
      float s = wsum[0] + wsum[1] + wsum[2] + wsum[3];
      s_scale = 1.0f / (sqrtf(s) + 1e-4f);
    }
    __syncthreads();
    const float sc = s_scale;
    bf16_t* orow = xb + (size_t)row * K_DIM;
#pragma unroll
    for (int i = 0; i < 4; ++i) {
      union { bf16_t h[4]; uint2 u; } p;
      p.h[0] = (bf16_t)(v[i].x * sc);
      p.h[1] = (bf16_t)(v[i].y * sc);
      p.h[2] = (bf16_t)(v[i].z * sc);
      p.h[3] = (bf16_t)(v[i].w * sc);
      ((uint2*)orow)[i * 256 + t] = p.u;
    }
  } else {
    const size_t idx = (size_t)(blockIdx.x - B_DIM) * 256 + t;  // one float4 each
    float4 a = ((const float4*)W)[idx];
    union { bf16_t h[4]; uint2 u; } p;
    p.h[0] = (bf16_t)a.x;
    p.h[1] = (bf16_t)a.y;
    p.h[2] = (bf16_t)a.z;
    p.h[3] = (bf16_t)a.w;
    ((uint2*)Wb)[idx] = p.u;
  }
}

// ---------------- kernel 2: 256x256 8-phase GEMM, C = A @ W^T + bias, ReLU --
// A: 8192x4096 bf16 rm; Bm: 4096x4096 bf16 rm (both K-major). BK=64.
// 8 waves (2M x 4N), per-wave 128x64 out = 8x4 frags of 16x16 (mfma 16x16x32).
// LDS 128 KiB: [buf(2)][mat(A,B)][half(2)][128 rows][64 cols] bf16,
// XOR-swizzled: byte ^= (row&7)<<4 (linear DMA dest + pre-swizzled gsrc).
// R8: proven R2 stage ledger (A(u+1)@P1/P2, B(u+2)@P3/P4, vmcnt(4)@P4) with
// (a) balanced per-phase ds_reads (P1:12, P2:4, P3:8 — LDS pipe never idle
// during an MFMA cluster), (b) kq-outer MFMA order (16 independent MFMAs per
// group, no same-acc back-to-back chains).
// Failed alternatives (measured): 32x32x16 shape (R3, bank conflicts), burst
// full-tile prefetch (R5), cross-buffer read-ahead (R6), A direct-to-reg (R7).
__global__ __launch_bounds__(512, 1) void gemm_kernel(
    const bf16_t* __restrict__ A, const bf16_t* __restrict__ Bm,
    const float* __restrict__ bias, float* __restrict__ C) {
  __shared__ __align__(16) char lds[131072];
  const int tid = threadIdx.x;
  const int lane = tid & 63, w = tid >> 6;
  const int wm = w >> 2, wn = w & 3;
  const int hi16 = lane >> 4;   // 0..3 (k-slot)
  const int r16 = lane & 15;

  // XCD-contiguous swizzle (512 blocks, 512 % 8 == 0 -> bijective)
  const int bid = blockIdx.x;
  const int sid = (bid & 7) * 64 + (bid >> 3);
  const int mb = sid & 31;      // 32 M-tiles
  const int nb = sid >> 5;      // 16 N-tiles (64 consecutive sids share 2 B-panels)

  const char* Ag = (const char*)(A + (size_t)mb * 256 * K_DIM);
  const char* Bg = (const char*)(Bm + (size_t)nb * 256 * K_DIM);

  // stage half-tile (mat 0=A,1=B; half h) of K-tile kt: 2 x gload_lds16/thread
  auto STAGE = [&](int mat, int h, int kt) {
    const int rbase = (kt & 1) * 65536 + mat * 32768 + h * 16384;
    const char* gb = (mat == 0 ? Ag : Bg) + (size_t)h * 128 * (K_DIM * 2) + kt * 128;
#pragma unroll
    for (int i = 0; i < 2; ++i) {
      const int qb = i * 8192 + w * 1024;          // wave-uniform LDS offset
      const int q = qb + lane * 16;                // this lane's linear slot
      const int r = q >> 7;                        // logical row (swizzle keeps row)
      const int cb = (q & 127) ^ ((r & 7) << 4);   // inverse-swizzled col byte
      gload_lds16(gb + (size_t)r * (K_DIM * 2) + cb, lds + rbase + qb);
    }
  };
  auto LDA = [&](int m, int kq, int cur) -> bf16x8 {
    const int r = m * 16 + r16;
    const int q = (r << 7) + (kq << 6) + hi16 * 16;
    return *(const bf16x8*)(lds + cur * 65536 + wm * 16384 + (q ^ ((r & 7) << 4)));
  };
  auto LDB = [&](int n, int kq, int cur) -> bf16x8 {
    const int r = (wn & 1) * 64 + n * 16 + r16;
    const int q = (r << 7) + (kq << 6) + hi16 * 16;
    return *(const bf16x8*)(lds + cur * 65536 + 32768 + (wn >> 1) * 16384 + (q ^ ((r & 7) << 4)));
  };

  f32x4 acc[8][4] = {};
  bf16x8 af[4][2], bfr[4][2];

  // prologue: A(T0).h0,h1  B(T0).h0,h1  B(T1).h0,h1 ; leave B(T1) in flight
  STAGE(0, 0, 0); STAGE(0, 1, 0); STAGE(1, 0, 0); STAGE(1, 1, 0);
  STAGE(1, 0, 1); STAGE(1, 1, 1);
  asm volatile("s_waitcnt vmcnt(4)" ::: "memory");
  BARRIER();

  for (int u = 0; u < 64; ++u) {
    const int cur = u & 1;
    const int un1 = (u + 1) & 63, un2 = (u + 2) & 63;  // wrap keeps parity, dead data
    // ---- P1: read af03 + bfr01 (12); stage A(T_{u+1}).h0; MFMA Q00
#pragma unroll
    for (int m = 0; m < 4; ++m)
#pragma unroll
      for (int kq = 0; kq < 2; ++kq) af[m][kq] = LDA(m, kq, cur);
#pragma unroll
    for (int n = 0; n < 2; ++n)
#pragma unroll
      for (int kq = 0; kq < 2; ++kq) bfr[n][kq] = LDB(n, kq, cur);
    STAGE(0, 0, un1);
    BARRIER();
    __builtin_amdgcn_s_setprio(1);
#pragma unroll
    for (int kq = 0; kq < 2; ++kq)
#pragma unroll
      for (int m = 0; m < 4; ++m)
#pragma unroll
        for (int n = 0; n < 2; ++n)
          acc[m][n] = __builtin_amdgcn_mfma_f32_16x16x32_bf16(af[m][kq], bfr[n][kq], acc[m][n], 0, 0, 0);
    __builtin_amdgcn_s_setprio(0);
    BARRIER();
    // ---- P2: read bfr23 (4); stage A(T_{u+1}).h1; MFMA Q01
#pragma unroll
    for (int n = 2; n < 4; ++n)
#pragma unroll
      for (int kq = 0; kq < 2; ++kq) bfr[n][kq] = LDB(n, kq, cur);
    STAGE(0, 1, un1);
    BARRIER();
    __builtin_amdgcn_s_setprio(1);
#pragma unroll
    for (int kq = 0; kq < 2; ++kq)
#pragma unroll
      for (int m = 0; m < 4; ++m)
#pragma unroll
        for (int n = 2; n < 4; ++n)
          acc[m][n] = __builtin_amdgcn_mfma_f32_16x16x32_bf16(af[m][kq], bfr[n][kq], acc[m][n], 0, 0, 0);
    __builtin_amdgcn_s_setprio(0);
    BARRIER();
    // ---- P3: read af47 (8, overwrite af); stage B(T_{u+2}).h0; MFMA Q10
#pragma unroll
    for (int m = 0; m < 4; ++m)
#pragma unroll
      for (int kq = 0; kq < 2; ++kq) af[m][kq] = LDA(m + 4, kq, cur);
    STAGE(1, 0, un2);
    BARRIER();
    __builtin_amdgcn_s_setprio(1);
#pragma unroll
    for (int kq = 0; kq < 2; ++kq)
#pragma unroll
      for (int m = 0; m < 4; ++m)
#pragma unroll
        for (int n = 0; n < 2; ++n)
          acc[m + 4][n] = __builtin_amdgcn_mfma_f32_16x16x32_bf16(af[m][kq], bfr[n][kq], acc[m + 4][n], 0, 0, 0);
    __builtin_amdgcn_s_setprio(0);
    BARRIER();
    // ---- P4: stage B(T_{u+2}).h1; MFMA Q11; counted gate vmcnt(4)
    STAGE(1, 1, un2);
    BARRIER();
    __builtin_amdgcn_s_setprio(1);
#pragma unroll
    for (int kq = 0; kq < 2; ++kq)
#pragma unroll
      for (int m = 0; m < 4; ++m)
#pragma unroll
        for (int n = 2; n < 4; ++n)
          acc[m + 4][n] = __builtin_amdgcn_mfma_f32_16x16x32_bf16(af[m][kq], bfr[n][kq], acc[m + 4][n], 0, 0, 0);
    __builtin_amdgcn_s_setprio(0);
    asm volatile("s_waitcnt vmcnt(4)" ::: "memory");  // leave B(T_{u+2}) in flight only
    BARRIER();
  }

  // epilogue: bias + ReLU, fp32 store. C/D map: col=lane&15, row=(lane>>4)*4+j
  float bv[4];
#pragma unroll
  for (int n = 0; n < 4; ++n) bv[n] = bias[nb * 256 + wn * 64 + n * 16 + r16];
#pragma unroll
  for (int m = 0; m < 8; ++m) {
    const int row0 = mb * 256 + wm * 128 + m * 16 + hi16 * 4;
#pragma unroll
    for (int j = 0; j < 4; ++j) {
      float* crow = C + (size_t)(row0 + j) * N_DIM + nb * 256 + wn * 64 + r16;
#pragma unroll
      for (int n = 0; n < 4; ++n)
        crow[n * 16] = fmaxf(acc[m][n][j] + bv[n], 0.f);
    }
  }
}

extern "C" void kernel_launch(void* const* d_in, const int* in_sizes, int n_in,
                              void* d_out, int out_size, void* d_ws, size_t ws_size,
                              hipStream_t stream) {
  const float* x = (const float*)d_in[0];
  const float* W = (const float*)d_in[1];
  const float* b = (const float*)d_in[2];
  float* out = (float*)d_out;

  bf16_t* xb = (bf16_t*)d_ws;                       // 8192*4096*2 = 64 MB
  bf16_t* Wb = xb + (size_t)B_DIM * K_DIM;          // 4096*4096*2 = 32 MB

  // 8192 norm blocks + 16384 W-convert blocks in one dispatch
  prep_kernel<<<B_DIM + (N_DIM * (size_t)K_DIM) / 4 / 256, 256, 0, stream>>>(x, W, xb, Wb);
  gemm_kernel<<<32 * 16, 512, 0, stream>>>(xb, Wb, b, out);
}

// Round 9
// 197.293 us; speedup vs baseline: 3.1817x; 1.5948x over previous
//
#include <hip/hip_runtime.h>
#include <hip/hip_bf16.h>
#include <stdint.h>
#include <stddef.h>

typedef int i32x4 __attribute__((ext_vector_type(4)));

#define B_DIM 8192
#define K_DIM 4096
#define N_DIM 4096

typedef __attribute__((address_space(1))) const void gvoid_t;
typedef __attribute__((address_space(3))) void lvoid_t;

__device__ __forceinline__ void gload_lds16(const void* g, void* l) {
  // width-16 global->LDS DMA; LDS dest is wave-uniform base + lane*16
  __builtin_amdgcn_global_load_lds((gvoid_t*)g, (lvoid_t*)l, 16, 0, 0);
}

#define FENCE() asm volatile("" ::: "memory")
#define BARRIER() do { FENCE(); __builtin_amdgcn_s_barrier(); FENCE(); } while (0)

__device__ __forceinline__ int q8(float v, float inv) {
  float f = v * inv;
  f = fminf(fmaxf(f, -127.f), 127.f);
  return __float2int_rn(f) & 0xff;
}

// ------- kernel 1 (merged prep): row L2-norm + int8 quant for x; int8 quant W
// x rows (blocks 0..8191): scale = 1/(||x||+1e-4); q = round(127*x/amax)
// (row scale cancels in quant); sa[row] = amax*scale/127.
// W rows (blocks 8192..12287): q = round(127*w/amax_row); sw[row] = amax/127.
__global__ __launch_bounds__(256) void prep_kernel(
    const float* __restrict__ x, const float* __restrict__ W,
    int8_t* __restrict__ xq, int8_t* __restrict__ wq,
    float* __restrict__ sa, float* __restrict__ sw) {
  const int t = threadIdx.x;
  const int lane = t & 63, wv = t >> 6;
  __shared__ float wsum[4], wamax[4];
  __shared__ float s_inv, s_scale;

  if (blockIdx.x < B_DIM) {
    const int row = blockIdx.x;
    const float4* xr = (const float4*)(x + (size_t)row * K_DIM);
    float4 v[4];
    float ss = 0.f, am = 0.f;
#pragma unroll
    for (int i = 0; i < 4; ++i) {
      v[i] = xr[i * 256 + t];
      ss += v[i].x * v[i].x + v[i].y * v[i].y + v[i].z * v[i].z + v[i].w * v[i].w;
      am = fmaxf(am, fmaxf(fmaxf(fabsf(v[i].x), fabsf(v[i].y)),
                           fmaxf(fabsf(v[i].z), fabsf(v[i].w))));
    }
#pragma unroll
    for (int o = 32; o > 0; o >>= 1) {
      ss += __shfl_down(ss, o, 64);
      am = fmaxf(am, __shfl_down(am, o, 64));
    }
    if (lane == 0) { wsum[wv] = ss; wamax[wv] = am; }
    __syncthreads();
    if (t == 0) {
      float s = wsum[0] + wsum[1] + wsum[2] + wsum[3];
      float a = fmaxf(fmaxf(wamax[0], wamax[1]), fmaxf(wamax[2], wamax[3]));
      a = fmaxf(a, 1e-20f);
      float sc = 1.0f / (sqrtf(s) + 1e-4f);
      s_inv = 127.0f / a;            // quantization multiplier
      s_scale = a * sc / 127.0f;     // dequant scale (includes row norm)
      sa[row] = s_scale;
    }
    __syncthreads();
    const float inv = s_inv;
    uint32_t* orow = (uint32_t*)(xq + (size_t)row * K_DIM);
#pragma unroll
    for (int i = 0; i < 4; ++i) {
      uint32_t p = (uint32_t)q8(v[i].x, inv) | ((uint32_t)q8(v[i].y, inv) << 8) |
                   ((uint32_t)q8(v[i].z, inv) << 16) | ((uint32_t)q8(v[i].w, inv) << 24);
      orow[i * 256 + t] = p;
    }
  } else {
    const int row = blockIdx.x - B_DIM;   // W output-channel row
    const float4* wr = (const float4*)(W + (size_t)row * K_DIM);
    float4 v[4];
    float am = 0.f;
#pragma unroll
    for (int i = 0; i < 4; ++i) {
      v[i] = wr[i * 256 + t];
      am = fmaxf(am, fmaxf(fmaxf(fabsf(v[i].x), fabsf(v[i].y)),
                           fmaxf(fabsf(v[i].z), fabsf(v[i].w))));
    }
#pragma unroll
    for (int o = 32; o > 0; o >>= 1) am = fmaxf(am, __shfl_down(am, o, 64));
    if (lane == 0) wamax[wv] = am;
    __syncthreads();
    if (t == 0) {
      float a = fmaxf(fmaxf(wamax[0], wamax[1]), fmaxf(wamax[2], wamax[3]));
      a = fmaxf(a, 1e-20f);
      s_inv = 127.0f / a;
      sw[row] = a / 127.0f;
    }
    __syncthreads();
    const float inv = s_inv;
    uint32_t* orow = (uint32_t*)(wq + (size_t)row * K_DIM);
#pragma unroll
    for (int i = 0; i < 4; ++i) {
      uint32_t p = (uint32_t)q8(v[i].x, inv) | ((uint32_t)q8(v[i].y, inv) << 8) |
                   ((uint32_t)q8(v[i].z, inv) << 16) | ((uint32_t)q8(v[i].w, inv) << 24);
      orow[i * 256 + t] = p;
    }
  }
}

// -------- kernel 2: 256x256 int8 8-phase GEMM, C = (Aq@Wq^T)*sa*sw + b, ReLU
// Aq: 8192x4096 i8 rm; Wq: 4096x4096 i8 rm (K-major). BK=128 i8 = 128 B/row —
// byte-identical tile geometry to the proven bf16 BK=64 kernel (R2/R8):
// same 128B rows, same XOR swizzle (0 conflicts), same STAGE/DMA, same LDS
// 128 KiB, same 4-phase ledger + vmcnt(4) gate. Iters halve: 32 K-tiles.
// mfma_i32_16x16x64_i8 (2x bf16 rate); i32 accumulation exact.
// 8 waves (2M x 4N), per-wave 128x64 out = 8x4 frags of 16x16.
__global__ __launch_bounds__(512, 1) void gemm_kernel(
    const int8_t* __restrict__ A, const int8_t* __restrict__ Bm,
    const float* __restrict__ sa, const float* __restrict__ sw,
    const float* __restrict__ bias, float* __restrict__ C) {
  __shared__ __align__(16) char lds[131072];
  const int tid = threadIdx.x;
  const int lane = tid & 63, w = tid >> 6;
  const int wm = w >> 2, wn = w & 3;
  const int hi16 = lane >> 4;   // 0..3 (k-slot)
  const int r16 = lane & 15;

  // XCD-contiguous swizzle (512 blocks, 512 % 8 == 0 -> bijective)
  const int bid = blockIdx.x;
  const int sid = (bid & 7) * 64 + (bid >> 3);
  const int mb = sid & 31;      // 32 M-tiles
  const int nb = sid >> 5;      // 16 N-tiles

  const char* Ag = (const char*)A + (size_t)mb * 256 * K_DIM;
  const char* Bg = (const char*)Bm + (size_t)nb * 256 * K_DIM;

  // stage half-tile (mat 0=A,1=B; half h) of K-tile kt: 2 x gload_lds16/thread
  // row byte-stride in global = K_DIM (i8); BK bytes = 128.
  auto STAGE = [&](int mat, int h, int kt) {
    const int rbase = (kt & 1) * 65536 + mat * 32768 + h * 16384;
    const char* gb = (mat == 0 ? Ag : Bg) + (size_t)h * 128 * K_DIM + kt * 128;
#pragma unroll
    for (int i = 0; i < 2; ++i) {
      const int qb = i * 8192 + w * 1024;          // wave-uniform LDS offset
      const int q = qb + lane * 16;                // this lane's linear slot
      const int r = q >> 7;                        // logical row (swizzle keeps row)
      const int cb = (q & 127) ^ ((r & 7) << 4);   // inverse-swizzled col byte
      gload_lds16(gb + (size_t)r * K_DIM + cb, lds + rbase + qb);
    }
  };
  // 16B/lane operand: k = kq*64 + hi16*16 + 0..15 (identical map A and B ->
  // any within-instruction k-permutation cancels between operands)
  auto LDA = [&](int m, int kq, int cur) -> i32x4 {
    const int r = m * 16 + r16;
    const int q = (r << 7) + (kq << 6) + hi16 * 16;
    return *(const i32x4*)(lds + cur * 65536 + wm * 16384 + (q ^ ((r & 7) << 4)));
  };
  auto LDB = [&](int n, int kq, int cur) -> i32x4 {
    const int r = (wn & 1) * 64 + n * 16 + r16;
    const int q = (r << 7) + (kq << 6) + hi16 * 16;
    return *(const i32x4*)(lds + cur * 65536 + 32768 + (wn >> 1) * 16384 + (q ^ ((r & 7) << 4)));
  };

  i32x4 acc[8][4] = {};
  i32x4 af[4][2], bfr[4][2];

  // prologue: A(T0).h0,h1  B(T0).h0,h1  B(T1).h0,h1 ; leave B(T1) in flight
  STAGE(0, 0, 0); STAGE(0, 1, 0); STAGE(1, 0, 0); STAGE(1, 1, 0);
  STAGE(1, 0, 1); STAGE(1, 1, 1);
  asm volatile("s_waitcnt vmcnt(4)" ::: "memory");
  BARRIER();

  for (int u = 0; u < 32; ++u) {
    const int cur = u & 1;
    const int un1 = (u + 1) & 31, un2 = (u + 2) & 31;  // wrap keeps parity, dead data
    // ---- P1: read af03 + bfr01; stage A(T_{u+1}).h0; MFMA Q00
#pragma unroll
    for (int m = 0; m < 4; ++m)
#pragma unroll
      for (int kq = 0; kq < 2; ++kq) af[m][kq] = LDA(m, kq, cur);
#pragma unroll
    for (int n = 0; n < 2; ++n)
#pragma unroll
      for (int kq = 0; kq < 2; ++kq) bfr[n][kq] = LDB(n, kq, cur);
    STAGE(0, 0, un1);
    BARRIER();
    __builtin_amdgcn_s_setprio(1);
#pragma unroll
    for (int kq = 0; kq < 2; ++kq)
#pragma unroll
      for (int m = 0; m < 4; ++m)
#pragma unroll
        for (int n = 0; n < 2; ++n)
          acc[m][n] = __builtin_amdgcn_mfma_i32_16x16x64_i8(af[m][kq], bfr[n][kq], acc[m][n], 0, 0, 0);
    __builtin_amdgcn_s_setprio(0);
    BARRIER();
    // ---- P2: read bfr23; stage A(T_{u+1}).h1; MFMA Q01
#pragma unroll
    for (int n = 2; n < 4; ++n)
#pragma unroll
      for (int kq = 0; kq < 2; ++kq) bfr[n][kq] = LDB(n, kq, cur);
    STAGE(0, 1, un1);
    BARRIER();
    __builtin_amdgcn_s_setprio(1);
#pragma unroll
    for (int kq = 0; kq < 2; ++kq)
#pragma unroll
      for (int m = 0; m < 4; ++m)
#pragma unroll
        for (int n = 2; n < 4; ++n)
          acc[m][n] = __builtin_amdgcn_mfma_i32_16x16x64_i8(af[m][kq], bfr[n][kq], acc[m][n], 0, 0, 0);
    __builtin_amdgcn_s_setprio(0);
    BARRIER();
    // ---- P3: read af47 (overwrite af); stage B(T_{u+2}).h0; MFMA Q10
#pragma unroll
    for (int m = 0; m < 4; ++m)
#pragma unroll
      for (int kq = 0; kq < 2; ++kq) af[m][kq] = LDA(m + 4, kq, cur);
    STAGE(1, 0, un2);
    BARRIER();
    __builtin_amdgcn_s_setprio(1);
#pragma unroll
    for (int kq = 0; kq < 2; ++kq)
#pragma unroll
      for (int m = 0; m < 4; ++m)
#pragma unroll
        for (int n = 0; n < 2; ++n)
          acc[m + 4][n] = __builtin_amdgcn_mfma_i32_16x16x64_i8(af[m][kq], bfr[n][kq], acc[m + 4][n], 0, 0, 0);
    __builtin_amdgcn_s_setprio(0);
    BARRIER();
    // ---- P4: stage B(T_{u+2}).h1; MFMA Q11; counted gate vmcnt(4)
    STAGE(1, 1, un2);
    BARRIER();
    __builtin_amdgcn_s_setprio(1);
#pragma unroll
    for (int kq = 0; kq < 2; ++kq)
#pragma unroll
      for (int m = 0; m < 4; ++m)
#pragma unroll
        for (int n = 2; n < 4; ++n)
          acc[m + 4][n] = __builtin_amdgcn_mfma_i32_16x16x64_i8(af[m][kq], bfr[n][kq], acc[m + 4][n], 0, 0, 0);
    __builtin_amdgcn_s_setprio(0);
    asm volatile("s_waitcnt vmcnt(4)" ::: "memory");  // leave B(T_{u+2}) in flight only
    BARRIER();
  }

  // epilogue: y = acc * sa[row]*sw[col] + bias, ReLU, fp32 store.
  // C/D map: col=lane&15, row=(lane>>4)*4+j (dtype-independent, m121-128)
  float bv[4], sbn[4];
#pragma unroll
  for (int n = 0; n < 4; ++n) {
    const int col = nb * 256 + wn * 64 + n * 16 + r16;
    bv[n] = bias[col];
    sbn[n] = sw[col];
  }
#pragma unroll
  for (int m = 0; m < 8; ++m) {
    const int row0 = mb * 256 + wm * 128 + m * 16 + hi16 * 4;
#pragma unroll
    for (int j = 0; j < 4; ++j) {
      const float sv = sa[row0 + j];               // uniform per 16-lane group
      float* crow = C + (size_t)(row0 + j) * N_DIM + nb * 256 + wn * 64 + r16;
#pragma unroll
      for (int n = 0; n < 4; ++n)
        crow[n * 16] = fmaxf((float)acc[m][n][j] * (sv * sbn[n]) + bv[n], 0.f);
    }
  }
}

extern "C" void kernel_launch(void* const* d_in, const int* in_sizes, int n_in,
                              void* d_out, int out_size, void* d_ws, size_t ws_size,
                              hipStream_t stream) {
  const float* x = (const float*)d_in[0];
  const float* W = (const float*)d_in[1];
  const float* b = (const float*)d_in[2];
  float* out = (float*)d_out;

  int8_t* xq = (int8_t*)d_ws;                              // 32 MB
  int8_t* wq = xq + (size_t)B_DIM * K_DIM;                 // 16 MB
  float* sa = (float*)(wq + (size_t)N_DIM * K_DIM);        // 32 KB
  float* sw = sa + B_DIM;                                  // 16 KB

  // 8192 x-rows + 4096 W-rows, one block each
  prep_kernel<<<B_DIM + N_DIM, 256, 0, stream>>>(x, W, xq, wq, sa, sw);
  gemm_kernel<<<32 * 16, 512, 0, stream>>>(xq, wq, sa, sw, b, out);
}